// Round 1
// baseline (9844.303 us; speedup 1.0000x reference)
//
#include <hip/hip_runtime.h>
#include <hip/hip_bf16.h>
#include <cstdint>
#include <cstddef>

// WaveNet forward, fp32 baseline.
//   B=4, T=8192, NC=256, NMEL=640, NL=8, K=3 (dilated 2^i)
// Structure per layer i:
//   pre[512][t] = in_b + cond_b + in_w[i] (x) audio  (k=3, dil)  + cond_w_slice @ spect
//   acts = tanh(pre[:256]) * sigmoid(pre[256:])
//   rsa  = rs_w[i] @ acts + rs_b ; audio += rsa[:256]; output += rsa[256:]
// cond conv fused into layer GEMM (K = 640 + 768 = 1408); gate fused into epilogue
// by pairing rows c / c+256 in one workgroup (m-tile = 32 low rows + 32 high rows).

constexpr int T_LEN = 8192;
constexpr int NB    = 4;
constexpr int NC    = 256;
constexpr int NMEL  = 640;
constexpr int NL    = 8;

// ---------------------------------------------------------------- start conv
__global__ __launch_bounds__(256) void start_kernel(
    const float* __restrict__ audio_in,  // (B,4,T)
    const float* __restrict__ start_w,   // (256,4)
    const float* __restrict__ start_b,   // (256)
    float* __restrict__ audio,           // (B,256,T) ws
    float* __restrict__ outbuf)          // (B,256,T) ws -> zero
{
    int idx = blockIdx.x * 256 + threadIdx.x;      // B*NC*T threads
    int t = idx & (T_LEN - 1);
    int c = (idx >> 13) & (NC - 1);
    int b = idx >> 21;
    float acc = start_b[c];
    #pragma unroll
    for (int a = 0; a < 4; ++a)
        acc += start_w[c * 4 + a] * audio_in[((size_t)b * 4 + a) * T_LEN + t];
    audio[idx]  = acc;
    outbuf[idx] = 0.f;
}

// ------------------------------------------- fused in-conv + cond + gate
// GEMM: C[64 x 64] tile of (512 x 32768), K = 1408.
// m-tile my covers rows {my*32 .. my*32+31} U {256+my*32 .. 256+my*32+31}.
__global__ __launch_bounds__(256) void layer_fused_kernel(
    const float* __restrict__ audio,     // (B,256,T) ws
    const float* __restrict__ spect,     // (B,640,T) input
    const float* __restrict__ in_w_l,    // (512,256,3)
    const float* __restrict__ cond_w_l,  // (512,640)
    const float* __restrict__ in_b_l,    // (512)
    const float* __restrict__ cond_b_l,  // (512)
    float* __restrict__ acts,            // (B,256,T) ws
    int dilation)
{
    constexpr int KTOT = NMEL + NC * 3;  // 1408 = 88 * 16
    __shared__ __align__(16) float As[16][68];   // A^T: As[k][m]
    __shared__ __align__(16) float Bs[16][68];   // Bs[k][n]
    __shared__ float Cs[64][65];                 // result tile for gate pairing

    const int tid = threadIdx.x;
    const int tx = tid & 15, ty = tid >> 4;
    const int n0 = blockIdx.x * 64;              // time offset
    const int my = blockIdx.y;                   // 0..7
    const int b  = blockIdx.z;

    const float* spect_b = spect + (size_t)b * NMEL * T_LEN;
    const float* audio_b = audio + (size_t)b * NC * T_LEN;

    // A staging: thread -> (m = tid>>2, 4 consecutive k at (tid&3)*4)
    const int a_m = tid >> 2;
    const int a_k = (tid & 3) * 4;
    const int gm_a = (a_m < 32) ? (my * 32 + a_m) : (224 + my * 32 + a_m);
    // B staging: thread -> (col = tid&63, k rows (tid>>6) + 4j)
    const int b_n = tid & 63;
    const int b_r = tid >> 6;

    float acc[4][4] = {};

    for (int k0 = 0; k0 < KTOT; k0 += 16) {
        // ---- stage A (weights), float4 coalesced; 16-tiles never straddle 640
        int ka = k0 + a_k;
        float4 av;
        if (ka < NMEL)
            av = *(const float4*)&cond_w_l[(size_t)gm_a * NMEL + ka];
        else
            av = *(const float4*)&in_w_l[(size_t)gm_a * (NC * 3) + (ka - NMEL)];
        As[a_k + 0][a_m] = av.x;
        As[a_k + 1][a_m] = av.y;
        As[a_k + 2][a_m] = av.z;
        As[a_k + 3][a_m] = av.w;

        // ---- stage B (inputs)
        #pragma unroll
        for (int j = 0; j < 4; ++j) {
            int k  = b_r + j * 4;
            int gk = k0 + k;
            float v;
            if (gk < NMEL) {
                v = spect_b[(size_t)gk * T_LEN + n0 + b_n];
            } else {
                int rr = gk - NMEL;
                int cc = rr / 3;
                int kk = rr - cc * 3;            // tap 0,1,2 -> offset -d,0,+d
                int tg = n0 + b_n + (kk - 1) * dilation;
                v = (tg >= 0 && tg < T_LEN) ? audio_b[(size_t)cc * T_LEN + tg] : 0.f;
            }
            Bs[k][b_n] = v;
        }
        __syncthreads();

        #pragma unroll
        for (int kk = 0; kk < 16; ++kk) {
            float4 a4 = *(const float4*)&As[kk][ty * 4];
            float4 b4 = *(const float4*)&Bs[kk][tx * 4];
            float ar[4] = {a4.x, a4.y, a4.z, a4.w};
            float br[4] = {b4.x, b4.y, b4.z, b4.w};
            #pragma unroll
            for (int i = 0; i < 4; ++i)
                #pragma unroll
                for (int j = 0; j < 4; ++j)
                    acc[i][j] += ar[i] * br[j];
        }
        __syncthreads();
    }

    // ---- bias + stash tile for cross-row gate pairing
    #pragma unroll
    for (int i = 0; i < 4; ++i) {
        int rm = ty * 4 + i;
        int gm = (rm < 32) ? (my * 32 + rm) : (224 + my * 32 + rm);
        float bias = in_b_l[gm] + cond_b_l[gm];
        #pragma unroll
        for (int j = 0; j < 4; ++j)
            Cs[rm][tx * 4 + j] = acc[i][j] + bias;
    }
    __syncthreads();

    // ---- gate: acts[c] = tanh(pre[c]) * sigmoid(pre[c+256])
    float* acts_b = acts + (size_t)b * NC * T_LEN;
    #pragma unroll
    for (int e = 0; e < 8; ++e) {
        int idx = tid + e * 256;     // 0..2047
        int r  = idx >> 6;           // 0..31
        int cn = idx & 63;
        float p0 = Cs[r][cn];
        float p1 = Cs[r + 32][cn];
        float g  = tanhf(p0) * (1.f / (1.f + __expf(-p1)));
        acts_b[(size_t)(my * 32 + r) * T_LEN + n0 + cn] = g;
    }
}

// ------------------------------------------------- residual/skip 1x1 conv
__global__ __launch_bounds__(256) void rs_kernel(
    const float* __restrict__ acts,     // (B,256,T) ws
    const float* __restrict__ rs_w_l,   // (M,256)
    const float* __restrict__ rs_b_l,   // (M)
    float* __restrict__ audio,          // (B,256,T) ws (+= rows < 256)
    float* __restrict__ outbuf,         // (B,256,T) ws (+= rows >= 256)
    int all_to_output)                  // last layer: M=256, all rows -> output
{
    __shared__ __align__(16) float As[16][68];
    __shared__ __align__(16) float Bs[16][68];

    const int tid = threadIdx.x;
    const int tx = tid & 15, ty = tid >> 4;
    const int n0 = blockIdx.x * 64;
    const int m0 = blockIdx.y * 64;
    const int b  = blockIdx.z;

    const float* acts_b = acts + (size_t)b * NC * T_LEN;
    const int a_m = tid >> 2;
    const int a_k = (tid & 3) * 4;
    const int b_n = tid & 63;
    const int b_r = tid >> 6;

    float acc[4][4] = {};

    for (int k0 = 0; k0 < NC; k0 += 16) {
        float4 av = *(const float4*)&rs_w_l[(size_t)(m0 + a_m) * NC + k0 + a_k];
        As[a_k + 0][a_m] = av.x;
        As[a_k + 1][a_m] = av.y;
        As[a_k + 2][a_m] = av.z;
        As[a_k + 3][a_m] = av.w;
        #pragma unroll
        for (int j = 0; j < 4; ++j) {
            int k = b_r + j * 4;
            Bs[k][b_n] = acts_b[(size_t)(k0 + k) * T_LEN + n0 + b_n];
        }
        __syncthreads();
        #pragma unroll
        for (int kk = 0; kk < 16; ++kk) {
            float4 a4 = *(const float4*)&As[kk][ty * 4];
            float4 b4 = *(const float4*)&Bs[kk][tx * 4];
            float ar[4] = {a4.x, a4.y, a4.z, a4.w};
            float br[4] = {b4.x, b4.y, b4.z, b4.w};
            #pragma unroll
            for (int i = 0; i < 4; ++i)
                #pragma unroll
                for (int j = 0; j < 4; ++j)
                    acc[i][j] += ar[i] * br[j];
        }
        __syncthreads();
    }

    #pragma unroll
    for (int i = 0; i < 4; ++i) {
        int gm = m0 + ty * 4 + i;
        float bias = rs_b_l[gm];
        #pragma unroll
        for (int j = 0; j < 4; ++j) {
            int tcol = n0 + tx * 4 + j;
            float v = acc[i][j] + bias;
            if (all_to_output) {
                float* p = &outbuf[((size_t)b * NC + gm) * T_LEN + tcol];
                *p += v;
            } else if (gm < NC) {
                float* p = &audio[((size_t)b * NC + gm) * T_LEN + tcol];
                *p += v;
            } else {
                float* p = &outbuf[((size_t)b * NC + (gm - NC)) * T_LEN + tcol];
                *p += v;
            }
        }
    }
}

// ---------------------------------------------------------------- end conv
__global__ __launch_bounds__(256) void end_kernel(
    const float* __restrict__ outbuf,   // (B,256,T) ws
    const float* __restrict__ end_w,    // (8,256)
    const float* __restrict__ end_b,    // (8)
    float* __restrict__ out)            // (B,8,T)
{
    int idx = blockIdx.x * 256 + threadIdx.x;  // B*T threads
    int t = idx & (T_LEN - 1);
    int b = idx >> 13;
    const float* ob = outbuf + (size_t)b * NC * T_LEN;
    float acc[8];
    #pragma unroll
    for (int o = 0; o < 8; ++o) acc[o] = end_b[o];
    for (int c = 0; c < NC; ++c) {
        float x = ob[(size_t)c * T_LEN + t];
        #pragma unroll
        for (int o = 0; o < 8; ++o) acc[o] += end_w[o * NC + c] * x;
    }
    #pragma unroll
    for (int o = 0; o < 8; ++o)
        out[((size_t)b * 8 + o) * T_LEN + t] = acc[o];
}

// ---------------------------------------------------------------- launcher
extern "C" void kernel_launch(void* const* d_in, const int* in_sizes, int n_in,
                              void* d_out, int out_size, void* d_ws, size_t ws_size,
                              hipStream_t stream)
{
    const float* spect    = (const float*)d_in[0];
    const float* audio_in = (const float*)d_in[1];
    const float* start_w  = (const float*)d_in[2];
    const float* start_b  = (const float*)d_in[3];
    const float* cond_w   = (const float*)d_in[4];
    const float* cond_b   = (const float*)d_in[5];
    const float* in_w     = (const float*)d_in[6];
    const float* in_b     = (const float*)d_in[7];
    const float* rs_w     = (const float*)d_in[8];
    const float* rs_b     = (const float*)d_in[9];
    const float* end_w    = (const float*)d_in[10];
    const float* end_b    = (const float*)d_in[11];
    float* out = (float*)d_out;

    // ws layout: audio | acts | outbuf, each B*NC*T floats (33.55 MB) -> 100.7 MB
    const size_t npc = (size_t)NB * NC * T_LEN;   // 8,388,608
    float* audio  = (float*)d_ws;
    float* acts   = audio + npc;
    float* outbuf = acts + npc;

    start_kernel<<<dim3((unsigned)(npc / 256)), 256, 0, stream>>>(
        audio_in, start_w, start_b, audio, outbuf);

    for (int i = 0; i < NL; ++i) {
        int dil = 1 << i;
        layer_fused_kernel<<<dim3(T_LEN / 64 * 1, 8, NB), 256, 0, stream>>>(
            audio, spect,
            in_w   + (size_t)i * 512 * NC * 3,
            cond_w + (size_t)i * 512 * NMEL,
            in_b   + (size_t)i * 512,
            cond_b + (size_t)i * 512,
            acts, dil);
        int mrows = (i == NL - 1) ? NC : 2 * NC;
        rs_kernel<<<dim3(T_LEN / 64, mrows / 64, NB), 256, 0, stream>>>(
            acts,
            rs_w + (size_t)i * 2 * NC * NC,
            rs_b + (size_t)i * 2 * NC,
            audio, outbuf,
            (i == NL - 1) ? 1 : 0);
    }

    end_kernel<<<dim3(NB * T_LEN / 256), 256, 0, stream>>>(outbuf, end_w, end_b, out);
}

// Round 3
// 1316.306 us; speedup vs baseline: 7.4787x; 7.4787x over previous
//
#include <hip/hip_runtime.h>
#include <hip/hip_bf16.h>
#include <cstdint>
#include <cstddef>

// WaveNet forward, fp16-MFMA version.
//   B=4, T=8192, NC=256, NMEL=640, NL=8, K=3 (dilated 2^i)
// Per layer (one kernel): pre[512][t] = bias + W1[512][1408] @ X[1408][t]
//   where X = [spect(640) ; audio taps (3*256, tap-major)], then
//   acts = tanh(pre[:256])*sigmoid(pre[256:]) (paired in-wave), then
//   rsa = RS[512][256] @ acts ; audio_out = audio_in + rsa[:256] (ping-pong),
//   outbuf += rsa[256:]. Last layer: outbuf += rsa[:256] only.
// MFMA: v_mfma_f32_16x16x32_f16. Wave tile 64x64 (4x4 frags of 16x16).
// WG: 512 thr = 8 waves covering all 512 rows x 64 cols -> rs fusable.

constexpr int T_LEN = 8192;
constexpr int NB    = 4;
constexpr int NC    = 256;
constexpr int NMEL  = 640;
constexpr int NL    = 8;
constexpr int KTOT  = NMEL + 3 * NC;      // 1408 = 22 * 64

typedef _Float16 half8 __attribute__((ext_vector_type(8)));
typedef float f32x4 __attribute__((ext_vector_type(4)));
typedef unsigned short us8 __attribute__((ext_vector_type(8)));

__device__ __forceinline__ int base_m(int m, int w) {
    return (m < 2) ? (32 * w + 16 * m) : (256 + 32 * w + 16 * (m - 2));
}

// ---- A-fragment loads (weights, fp16, from L2): 8x dwordx4 per step
__device__ __forceinline__ void load_A(const _Float16* __restrict__ W, int k0,
                                       int lr, int lq, int w, half8 (&a)[2][4]) {
    #pragma unroll
    for (int m = 0; m < 4; ++m) {
        const _Float16* rp = W + (size_t)(base_m(m, w) + lr) * KTOT + lq * 8 + k0;
        #pragma unroll
        for (int h = 0; h < 2; ++h)
            a[h][m] = *(const half8*)(rp + 32 * h);
    }
}

// ---- B staging: 8 source elems -> one us8 (one ds_write_b128)
template<bool SH>
__device__ __forceinline__ us8 stage_ld(const float* __restrict__ sf,
                                        const _Float16* __restrict__ sh,
                                        const _Float16* __restrict__ aud,
                                        int kblk, int t0, int ks, int dil) {
    us8 sv;
    if (kblk < NMEL) {                      // wave-uniform branch (640 = 10*64)
        #pragma unroll
        for (int j = 0; j < 8; ++j) {
            int k = kblk + ks + j;
            unsigned short u;
            if (SH) {
                u = __builtin_bit_cast(unsigned short, sh[(size_t)k * T_LEN + t0]);
            } else {
                _Float16 h = (_Float16)sf[(size_t)k * T_LEN + t0];
                u = __builtin_bit_cast(unsigned short, h);
            }
            sv[j] = u;
        }
    } else {
        #pragma unroll
        for (int j = 0; j < 8; ++j) {
            int kin = kblk + ks + j - NMEL;
            int kk = kin >> 8, cc = kin & 255;     // tap-major packing
            int t = t0 + (kk - 1) * dil;
            unsigned short u = 0;
            if (t >= 0 && t < T_LEN)
                u = __builtin_bit_cast(unsigned short, aud[(size_t)cc * T_LEN + t]);
            sv[j] = u;
        }
    }
    return sv;
}

__device__ __forceinline__ void read_B(half8 (&bF)[2][4],
                                       const _Float16 (*Bsb)[72], int lr, int lq) {
    #pragma unroll
    for (int h = 0; h < 2; ++h)
        #pragma unroll
        for (int n = 0; n < 4; ++n)
            bF[h][n] = *(const half8*)&Bsb[16 * n + lr][32 * h + lq * 8];
}

__device__ __forceinline__ void mfma_all(f32x4 (&acc)[4][4],
                                         const half8 (&a)[2][4],
                                         const half8 (&b)[2][4]) {
    #pragma unroll
    for (int h = 0; h < 2; ++h)
        #pragma unroll
        for (int m = 0; m < 4; ++m)
            #pragma unroll
            for (int n = 0; n < 4; ++n)
                acc[m][n] = __builtin_amdgcn_mfma_f32_16x16x32_f16(
                    a[h][m], b[h][n], acc[m][n], 0, 0, 0);
}

// ------------------------------------------------------------- layer kernel
template<bool SH>
__global__ __launch_bounds__(512, 2) void wavenet_layer(
    const _Float16* __restrict__ audio_rd,   // (256,T) per batch, ping
    _Float16* __restrict__ audio_wr,         // pong
    const float* __restrict__ spect_f,       // (B,640,T) fp32 input
    const _Float16* __restrict__ spect_h,    // optional fp16 copy
    const _Float16* __restrict__ W1l,        // (512,1408) fp16
    const float* __restrict__ bias1_l,       // (512) in_b+cond_b
    const _Float16* __restrict__ RSl,        // (512,256) fp16
    const float* __restrict__ rs_b_l,        // (512)
    float* __restrict__ outbuf,              // (B,256,T) fp32 accum
    int dil, int last)
{
    __shared__ __align__(16) _Float16 Bs[2][64][72];   // dbuf B tile, 144B stride
    __shared__ __align__(16) _Float16 acts_s[64][264]; // [col][chan], 528B stride

    const int tid = threadIdx.x;
    const int l  = tid & 63;
    const int w  = tid >> 6;
    const int lr = l & 15;
    const int lq = l >> 4;
    const int col = tid & 63;                // staging col
    const int ks  = (tid >> 6) * 8;          // staging k-subblock
    const int n0 = blockIdx.x * 64;
    const int b  = blockIdx.z;
    const int t0 = n0 + col;

    const float*    spect_fb = spect_f + (size_t)b * NMEL * T_LEN;
    const _Float16* spect_hb = spect_h + (size_t)b * NMEL * T_LEN;
    const _Float16* aud_rd   = audio_rd + (size_t)b * NC * T_LEN;
    _Float16*       aud_wr   = audio_wr + (size_t)b * NC * T_LEN;
    float*          out_b    = outbuf + (size_t)b * NC * T_LEN;

    const f32x4 fzero = {0.f, 0.f, 0.f, 0.f};
    f32x4 acc[4][4];
    #pragma unroll
    for (int m = 0; m < 4; ++m)
        #pragma unroll
        for (int n = 0; n < 4; ++n) acc[m][n] = fzero;

    half8 aA[2][4], aB[2][4];

    // prologue: stage k-block 0, preload A(0)
    {
        us8 sv = stage_ld<SH>(spect_fb, spect_hb, aud_rd, 0, t0, ks, dil);
        *(us8*)&Bs[0][col][ks] = sv;
        load_A(W1l, 0, lr, lq, w, aA);
        __syncthreads();
    }

#define STEP(ACUR, ANXT, BR, BW, IT)                                           \
    {                                                                          \
        const int kn_ = ((IT) < 21 ? (IT) + 1 : 21) * 64;                      \
        us8 sv_ = stage_ld<SH>(spect_fb, spect_hb, aud_rd, kn_, t0, ks, dil);  \
        load_A(W1l, kn_, lr, lq, w, ANXT);                                     \
        half8 bF_[2][4];                                                       \
        read_B(bF_, Bs[BR], lr, lq);                                           \
        mfma_all(acc, ACUR, bF_);                                              \
        *(us8*)&Bs[BW][col][ks] = sv_;                                         \
        __syncthreads();                                                       \
    }

    for (int itp = 0; itp < 11; ++itp) {
        STEP(aA, aB, 0, 1, itp * 2);
        STEP(aB, aA, 1, 0, itp * 2 + 1);
    }
#undef STEP

    // ---- gate: acts[c] = tanh(pre[c]) * sigmoid(pre[c+256]); frag m pairs m+2
    float bias[4][4];
    #pragma unroll
    for (int m = 0; m < 4; ++m)
        #pragma unroll
        for (int r = 0; r < 4; ++r)
            bias[m][r] = bias1_l[base_m(m, w) + lq * 4 + r];

    #pragma unroll
    for (int m = 0; m < 2; ++m)
        #pragma unroll
        for (int n = 0; n < 4; ++n)
            #pragma unroll
            for (int r = 0; r < 4; ++r) {
                float p0 = acc[m][n][r] + bias[m][r];
                float p1 = acc[m + 2][n][r] + bias[m + 2][r];
                float th = 1.f - 2.f / (1.f + __expf(2.f * p0));
                float sg = 1.f / (1.f + __expf(-p1));
                int row = base_m(m, w) + lq * 4 + r;      // 0..255
                acts_s[16 * n + lr][row] = (_Float16)(th * sg);
            }
    __syncthreads();

    // ---- rs GEMM: K=256 from acts_s
    #pragma unroll
    for (int m = 0; m < 4; ++m)
        #pragma unroll
        for (int n = 0; n < 4; ++n) acc[m][n] = fzero;

    #pragma unroll
    for (int kstep = 0; kstep < 8; ++kstep) {
        half8 aR[4], bR[4];
        #pragma unroll
        for (int m = 0; m < 4; ++m)
            aR[m] = *(const half8*)&RSl[(size_t)(base_m(m, w) + lr) * NC +
                                        32 * kstep + lq * 8];
        #pragma unroll
        for (int n = 0; n < 4; ++n)
            bR[n] = *(const half8*)&acts_s[16 * n + lr][32 * kstep + lq * 8];
        #pragma unroll
        for (int m = 0; m < 4; ++m)
            #pragma unroll
            for (int n = 0; n < 4; ++n)
                acc[m][n] = __builtin_amdgcn_mfma_f32_16x16x32_f16(
                    aR[m], bR[n], acc[m][n], 0, 0, 0);
    }

    // ---- epilogue: route rsa
    #pragma unroll
    for (int m = 0; m < 4; ++m)
        #pragma unroll
        for (int n = 0; n < 4; ++n)
            #pragma unroll
            for (int r = 0; r < 4; ++r) {
                int gm = base_m(m, w) + lq * 4 + r;
                int t  = n0 + 16 * n + lr;
                float v = acc[m][n][r] + rs_b_l[gm];
                if (m < 2) {                         // gm < 256
                    if (last) {
                        out_b[(size_t)gm * T_LEN + t] += v;
                    } else {
                        size_t ai = (size_t)gm * T_LEN + t;
                        float an = (float)aud_rd[ai] + v;
                        aud_wr[ai] = (_Float16)an;
                    }
                } else if (!last) {
                    out_b[(size_t)(gm - 256) * T_LEN + t] += v;
                }
            }
}

// ------------------------------------------------------------- pack weights
__global__ __launch_bounds__(256) void pack_kernel(
    const float* __restrict__ cond_w, const float* __restrict__ in_w,
    const float* __restrict__ rs_w, const float* __restrict__ in_b,
    const float* __restrict__ cond_b,
    _Float16* __restrict__ W1h, _Float16* __restrict__ RSh,
    float* __restrict__ bias1)
{
    constexpr int SZ_W1 = NL * 512 * KTOT;       // 5,767,168
    constexpr int SZ_RS = NL * 512 * NC;         // 1,048,576
    int idx = blockIdx.x * 256 + threadIdx.x;
    if (idx < SZ_W1) {
        int l = idx / (512 * KTOT);
        int r1 = idx - l * (512 * KTOT);
        int m = r1 / KTOT;
        int k = r1 - m * KTOT;
        float v;
        if (k < NMEL) {
            v = cond_w[(size_t)(l * 512 + m) * NMEL + k];
        } else {
            int kin = k - NMEL;
            int kk = kin >> 8, cc = kin & 255;
            v = in_w[((size_t)(l * 512 + m) * NC + cc) * 3 + kk];
        }
        W1h[idx] = (_Float16)v;
    } else if (idx < SZ_W1 + SZ_RS) {
        int i2 = idx - SZ_W1;
        RSh[i2] = (_Float16)rs_w[i2];
    } else if (idx < SZ_W1 + SZ_RS + NL * 512) {
        int i3 = idx - SZ_W1 - SZ_RS;
        bias1[i3] = in_b[i3] + cond_b[i3];
    }
}

// ------------------------------------------------------------- spect -> fp16
__global__ __launch_bounds__(256) void spect_cvt_kernel(
    const float* __restrict__ spect, _Float16* __restrict__ spect_h)
{
    int idx = blockIdx.x * 256 + threadIdx.x;    // NB*NMEL*T threads
    spect_h[idx] = (_Float16)spect[idx];
}

// ------------------------------------------------------------- start conv
__global__ __launch_bounds__(256) void start_kernel(
    const float* __restrict__ audio_in,  // (B,4,T)
    const float* __restrict__ start_w,   // (256,4)
    const float* __restrict__ start_b,   // (256)
    _Float16* __restrict__ audio0,       // (B,256,T) fp16
    float* __restrict__ outbuf)          // (B,256,T) -> zero
{
    int idx = blockIdx.x * 256 + threadIdx.x;
    int t = idx & (T_LEN - 1);
    int c = (idx >> 13) & (NC - 1);
    int b = idx >> 21;
    float acc = start_b[c];
    #pragma unroll
    for (int a = 0; a < 4; ++a)
        acc += start_w[c * 4 + a] * audio_in[((size_t)b * 4 + a) * T_LEN + t];
    audio0[idx] = (_Float16)acc;
    outbuf[idx] = 0.f;
}

// ------------------------------------------------------------- end conv
__global__ __launch_bounds__(256) void end_kernel(
    const float* __restrict__ outbuf,
    const float* __restrict__ end_w,     // (8,256)
    const float* __restrict__ end_b,     // (8)
    float* __restrict__ out)             // (B,8,T)
{
    int idx = blockIdx.x * 256 + threadIdx.x;    // B*T threads
    int t = idx & (T_LEN - 1);
    int b = idx >> 13;
    const float* ob = outbuf + (size_t)b * NC * T_LEN;
    float acc[8];
    #pragma unroll
    for (int o = 0; o < 8; ++o) acc[o] = end_b[o];
    for (int c = 0; c < NC; ++c) {
        float x = ob[(size_t)c * T_LEN + t];
        #pragma unroll
        for (int o = 0; o < 8; ++o) acc[o] += end_w[o * NC + c] * x;
    }
    #pragma unroll
    for (int o = 0; o < 8; ++o)
        out[((size_t)b * 8 + o) * T_LEN + t] = acc[o];
}

// ------------------------------------------------------------- launcher
extern "C" void kernel_launch(void* const* d_in, const int* in_sizes, int n_in,
                              void* d_out, int out_size, void* d_ws, size_t ws_size,
                              hipStream_t stream)
{
    const float* spect    = (const float*)d_in[0];
    const float* audio_in = (const float*)d_in[1];
    const float* start_w  = (const float*)d_in[2];
    const float* start_b  = (const float*)d_in[3];
    const float* cond_w   = (const float*)d_in[4];
    const float* cond_b   = (const float*)d_in[5];
    const float* in_w     = (const float*)d_in[6];
    const float* in_b     = (const float*)d_in[7];
    const float* rs_w     = (const float*)d_in[8];
    const float* rs_b     = (const float*)d_in[9];
    const float* end_w    = (const float*)d_in[10];
    const float* end_b    = (const float*)d_in[11];
    float* out = (float*)d_out;

    // ws layout (bytes):
    //   W1h 11,534,336 | RSh 2,097,152 | bias1 16,384 | outbuf 33,554,432 |
    //   audio0 16,777,216 | audio1 16,777,216 | [spect_h 41,943,040]
    char* base = (char*)d_ws;
    _Float16* W1h    = (_Float16*)base;
    _Float16* RSh    = W1h + (size_t)NL * 512 * KTOT;
    float*    bias1  = (float*)(RSh + (size_t)NL * 512 * NC);
    float*    outbuf = bias1 + NL * 512;
    _Float16* audio0 = (_Float16*)(outbuf + (size_t)NB * NC * T_LEN);
    _Float16* audio1 = audio0 + (size_t)NB * NC * T_LEN;
    _Float16* spect_h = audio1 + (size_t)NB * NC * T_LEN;
    const bool use_sh = (ws_size >= 122699776u);

    pack_kernel<<<26640, 256, 0, stream>>>(cond_w, in_w, rs_w, in_b, cond_b,
                                           W1h, RSh, bias1);
    if (use_sh)
        spect_cvt_kernel<<<(NB * NMEL * T_LEN) / 256, 256, 0, stream>>>(spect, spect_h);
    start_kernel<<<(NB * NC * T_LEN) / 256, 256, 0, stream>>>(
        audio_in, start_w, start_b, audio0, outbuf);

    dim3 grid(T_LEN / 64, 1, NB);
    for (int i = 0; i < NL; ++i) {
        const _Float16* ard = (i & 1) ? audio1 : audio0;
        _Float16*       awr = (i & 1) ? audio0 : audio1;
        const _Float16* W1l = W1h + (size_t)i * 512 * KTOT;
        const _Float16* RSl = RSh + (size_t)i * 512 * NC;
        const float* b1l = bias1 + i * 512;
        const float* rbl = rs_b + i * 512;
        int dil = 1 << i;
        int last = (i == NL - 1) ? 1 : 0;
        if (use_sh)
            wavenet_layer<true><<<grid, 512, 0, stream>>>(
                ard, awr, spect, spect_h, W1l, b1l, RSl, rbl, outbuf, dil, last);
        else
            wavenet_layer<false><<<grid, 512, 0, stream>>>(
                ard, awr, spect, spect_h, W1l, b1l, RSl, rbl, outbuf, dil, last);
    }

    end_kernel<<<(NB * T_LEN) / 256, 256, 0, stream>>>(outbuf, end_w, end_b, out);
}

// Round 4
// 1085.671 us; speedup vs baseline: 9.0675x; 1.2124x over previous
//
#include <hip/hip_runtime.h>
#include <hip/hip_bf16.h>
#include <cstdint>
#include <cstddef>

// WaveNet forward, fp16-MFMA v2 (latency-optimized).
//   B=4, T=8192, NC=256, NMEL=640, NL=8, K=3 (dilated 2^i)
// One kernel per layer: pre[512][t] = bias + W1[512][1408] @ X[1408][t],
//   X = [spect(640) ; audio taps (3*256, tap-major)], gate pairs rows c/c+256
//   in-wave, rs GEMM fused (acts via LDS), audio ping-pong with zero guard
//   pads (no bounds masking), skip accumulated in fp16.
// WG: 512 thr = 8 waves, 512 rows x 128 cols. Wave w: rows {32w..32w+31} u
//   {256+32w..+31}, 4x8 frags of 16x16x32 MFMA. Grid 64x1x4 = 256 WGs (1/CU).
// LDS: Bs[2][128][72] (XOR-swizzled k) UNION acts[128][264] (XOR-swizzled chan).

constexpr int T_LEN = 8192;
constexpr int NB    = 4;
constexpr int NC    = 256;
constexpr int NMEL  = 640;
constexpr int NL    = 8;
constexpr int KTOT  = NMEL + 3 * NC;   // 1408 = 22 * 64
constexpr int GUARD = 128;             // >= max dilation
constexpr int TP    = T_LEN + 2 * GUARD;  // padded audio row stride (8448)
constexpr int NCOL  = 128;             // cols per WG

typedef _Float16 half8 __attribute__((ext_vector_type(8)));
typedef float f32x4 __attribute__((ext_vector_type(4)));
typedef unsigned short us8 __attribute__((ext_vector_type(8)));

__device__ __forceinline__ int base_m(int m, int w) {
    return (m < 2) ? (32 * w + 16 * m) : (256 + 32 * w + 16 * (m - 2));
}

__device__ __forceinline__ half8 ldg8(const _Float16* p, unsigned boff) {
    return *(const half8*)((const unsigned char*)p + boff);
}

// stage 16 k-strided halfs -> two us8 (spect region; fp16 copy or fp32 cvt)
template<bool SH>
__device__ __forceinline__ void stage_sp(const float* sf, const _Float16* shh,
                                         unsigned eidx, us8& lo, us8& hi) {
    #pragma unroll
    for (int j = 0; j < 8; ++j) {
        if (SH) {
            lo[j] = __builtin_bit_cast(unsigned short, shh[eidx + j * T_LEN]);
            hi[j] = __builtin_bit_cast(unsigned short, shh[eidx + (j + 8) * T_LEN]);
        } else {
            lo[j] = __builtin_bit_cast(unsigned short, (_Float16)sf[eidx + j * T_LEN]);
            hi[j] = __builtin_bit_cast(unsigned short, (_Float16)sf[eidx + (j + 8) * T_LEN]);
        }
    }
}
// audio region (always fp16, guard-padded rows of TP)
__device__ __forceinline__ void stage_au(const _Float16* a, unsigned eidx,
                                         us8& lo, us8& hi) {
    #pragma unroll
    for (int j = 0; j < 8; ++j) {
        lo[j] = __builtin_bit_cast(unsigned short, a[eidx + j * TP]);
        hi[j] = __builtin_bit_cast(unsigned short, a[eidx + (j + 8) * TP]);
    }
}

// ------------------------------------------------------------- layer kernel
template<bool SH>
__global__ __launch_bounds__(512, 2) void wavenet_layer(
    const _Float16* __restrict__ audio_rd,   // (B,256,TP) guard-padded, ping
    _Float16* __restrict__ audio_wr,         // pong
    const float* __restrict__ spect_f,       // (B,640,T) fp32 input
    const _Float16* __restrict__ spect_h,    // fp16 copy (if SH)
    const _Float16* __restrict__ W1l,        // (512,1408) fp16
    const float* __restrict__ bias1_l,       // (512) in_b+cond_b
    const _Float16* __restrict__ RSl,        // (512,256) fp16
    const float* __restrict__ rs_b_l,        // (512)
    _Float16* __restrict__ outbuf,           // (B,256,T) fp16 skip accum
    int dil, int last)
{
    // Bs region: buf*18432 + col*144 + kphys*2   (2*128*72 halfs = 36864 B)
    // acts region (union): col*528 + cphys*2     (128*264 halfs  = 67584 B)
    __shared__ __align__(16) unsigned char smem[67584];

    const int tid = threadIdx.x;
    const int l  = tid & 63;
    const int w  = tid >> 6;
    const int lr = l & 15;
    const int lq = l >> 4;
    const int u  = lr & 7;
    const int sc = tid & 127;      // staging col
    const int sg = tid >> 7;       // staging k-group (0..3), k-local 16*sg+j
    const int n0 = blockIdx.x * NCOL;
    const int b  = blockIdx.z;

    const float*    spect_fb = spect_f + (size_t)b * NMEL * T_LEN;
    const _Float16* spect_hb = spect_h + (size_t)b * NMEL * T_LEN;
    const _Float16* aud_rd   = audio_rd + (size_t)b * NC * TP;
    _Float16*       aud_wr   = audio_wr + (size_t)b * NC * TP;
    _Float16*       out_b    = outbuf + (size_t)b * NC * T_LEN;

    // LDS write addresses (thread-constant, XOR swizzle k' = k ^ 8*(col&7))
    const int wlo = sc * 144 + (((16 * sg)     ^ (8 * (sc & 7))) * 2);
    const int whi = sc * 144 + (((16 * sg + 8) ^ (8 * (sc & 7))) * 2);
    // LDS read bases per h (thread-constant): phys = 32*(h^u2) + 8*(lq^(u&3))
    const int u2 = u >> 2;
    const int rb0 = lr * 144 + ((32 * (0 ^ u2) + 8 * (lq ^ (u & 3))) * 2);
    const int rb1 = lr * 144 + ((32 * (1 ^ u2) + 8 * (lq ^ (u & 3))) * 2);

    // A byte-offsets (4 thread-constant bases, +128 B per K-step, h via imm)
    unsigned voffA[4];
    #pragma unroll
    for (int m = 0; m < 4; ++m)
        voffA[m] = (unsigned)(((base_m(m, w) + lr) * KTOT + 8 * lq) * 2);

    // B staging element-offsets (incremental)
    unsigned voffS  = (unsigned)((128 + 16 * sg) * T_LEN + n0 + sc);   // block ss=2
    unsigned voffAu = (unsigned)((16 * sg) * TP + GUARD + n0 + sc - dil); // ss=10

    const f32x4 fzero = {0.f, 0.f, 0.f, 0.f};
    f32x4 acc[4][8];
    #pragma unroll
    for (int m = 0; m < 4; ++m)
        #pragma unroll
        for (int n = 0; n < 8; ++n) acc[m][n] = fzero;

    us8 plo[2], phi[2];

    // prologue: stage blocks 0,1; write block 0; barrier
    stage_sp<SH>(spect_fb, spect_hb, (unsigned)((16 * sg) * T_LEN + n0 + sc),
                 plo[0], phi[0]);
    stage_sp<SH>(spect_fb, spect_hb, (unsigned)((64 + 16 * sg) * T_LEN + n0 + sc),
                 plo[1], phi[1]);
    *(us8*)(smem + wlo) = plo[0];
    *(us8*)(smem + whi) = phi[0];
    __syncthreads();

#define MFMA_BODY(CUR)                                                        \
    _Pragma("unroll") for (int h = 0; h < 2; ++h) {                           \
        half8 bf[8];                                                          \
        _Pragma("unroll") for (int n = 0; n < 8; ++n)                         \
            bf[n] = *(const half8*)(smem + 18432 * (CUR) +                    \
                                    (h ? rb1 : rb0) + 2304 * n);              \
        _Pragma("unroll") for (int m = 0; m < 4; ++m)                         \
            _Pragma("unroll") for (int n = 0; n < 8; ++n)                     \
                acc[m][n] = __builtin_amdgcn_mfma_f32_16x16x32_f16(           \
                    aAh[h][m], bf[n], acc[m][n], 0, 0, 0);                    \
    }

#define HSTEP(CUR, SS)                                                        \
    {                                                                         \
        half8 aAh[2][4];                                                      \
        _Pragma("unroll") for (int h = 0; h < 2; ++h)                         \
            _Pragma("unroll") for (int m = 0; m < 4; ++m)                     \
                aAh[h][m] = ldg8(W1l, voffA[m] + 64 * h);                     \
        if ((SS) < 10) {                                                      \
            stage_sp<SH>(spect_fb, spect_hb, voffS, plo[CUR], phi[CUR]);      \
            voffS += 64u * T_LEN;                                             \
        } else {                                                              \
            stage_au(aud_rd, voffAu, plo[CUR], phi[CUR]);                     \
            voffAu += ((SS) == 13 || (SS) == 17)                              \
                          ? (unsigned)(dil - 192 * TP)                        \
                          : (unsigned)(64 * TP);                              \
        }                                                                     \
        *(us8*)(smem + 18432 * ((CUR) ^ 1) + wlo) = plo[(CUR) ^ 1];           \
        *(us8*)(smem + 18432 * ((CUR) ^ 1) + whi) = phi[(CUR) ^ 1];           \
        MFMA_BODY(CUR)                                                        \
        _Pragma("unroll") for (int m = 0; m < 4; ++m) voffA[m] += 128;        \
        __syncthreads();                                                      \
    }

    for (int it = 0; it < 20; it += 2) {
        HSTEP(0, it + 2)
        HSTEP(1, it + 3)
    }
    // peeled step 20: no stage; write block 21; compute Bs[0]
    {
        half8 aAh[2][4];
        #pragma unroll
        for (int h = 0; h < 2; ++h)
            #pragma unroll
            for (int m = 0; m < 4; ++m)
                aAh[h][m] = ldg8(W1l, voffA[m] + 64 * h);
        *(us8*)(smem + 18432 + wlo) = plo[1];
        *(us8*)(smem + 18432 + whi) = phi[1];
        MFMA_BODY(0)
        #pragma unroll
        for (int m = 0; m < 4; ++m) voffA[m] += 128;
        __syncthreads();
    }
    // peeled step 21: compute Bs[1]
    {
        half8 aAh[2][4];
        #pragma unroll
        for (int h = 0; h < 2; ++h)
            #pragma unroll
            for (int m = 0; m < 4; ++m)
                aAh[h][m] = ldg8(W1l, voffA[m] + 64 * h);
        MFMA_BODY(1)
        __syncthreads();   // all Bs reads done -> acts may overwrite union
    }
#undef HSTEP
#undef MFMA_BODY

    // ---- gate: acts[c] = tanh(pre[c]) * sigmoid(pre[c+256]); frag m pairs m+2
    float bias[4][4];
    #pragma unroll
    for (int m = 0; m < 4; ++m)
        #pragma unroll
        for (int r = 0; r < 4; ++r)
            bias[m][r] = bias1_l[base_m(m, w) + 4 * lq + r];

    #pragma unroll
    for (int m = 0; m < 2; ++m)
        #pragma unroll
        for (int n = 0; n < 8; ++n)
            #pragma unroll
            for (int r = 0; r < 4; ++r) {
                float p0 = acc[m][n][r] + bias[m][r];
                float p1 = acc[m + 2][n][r] + bias[m + 2][r];
                float th = 1.f - 2.f / (1.f + __expf(2.f * p0));
                float sgm = 1.f / (1.f + __expf(-p1));
                int chan  = base_m(m, w) + 4 * lq + r;        // 0..255
                int col   = 16 * n + lr;
                int cphys = chan ^ (8 * (lr & 7));
                *(_Float16*)(smem + col * 528 + cphys * 2) = (_Float16)(th * sgm);
            }
    __syncthreads();

    // ---- rs GEMM: K=256 from acts (swizzled)
    #pragma unroll
    for (int m = 0; m < 4; ++m)
        #pragma unroll
        for (int n = 0; n < 8; ++n) acc[m][n] = fzero;

    unsigned voffR[4];
    #pragma unroll
    for (int m = 0; m < 4; ++m)
        voffR[m] = (unsigned)(((base_m(m, w) + lr) * NC + 8 * lq) * 2);

    #pragma unroll
    for (int ks = 0; ks < 8; ++ks) {
        half8 aR[4], bR[8];
        #pragma unroll
        for (int m = 0; m < 4; ++m)
            aR[m] = ldg8(RSl, voffR[m] + 64 * ks);
        const int cph = (32 * ks + 8 * lq) ^ (8 * u);
        #pragma unroll
        for (int n = 0; n < 8; ++n)
            bR[n] = *(const half8*)(smem + (16 * n + lr) * 528 + cph * 2);
        #pragma unroll
        for (int m = 0; m < 4; ++m)
            #pragma unroll
            for (int n = 0; n < 8; ++n)
                acc[m][n] = __builtin_amdgcn_mfma_f32_16x16x32_f16(
                    aR[m], bR[n], acc[m][n], 0, 0, 0);
    }

    // ---- epilogue: route rsa
    #pragma unroll
    for (int m = 0; m < 4; ++m) {
        const int gm = base_m(m, w) + 4 * lq;   // + r
        #pragma unroll
        for (int r = 0; r < 4; ++r) {
            float rb = rs_b_l[gm + r];
            #pragma unroll
            for (int n = 0; n < 8; ++n) {
                int t = n0 + 16 * n + lr;
                float v = acc[m][n][r] + rb;
                if (m < 2) {                     // channels 0..255
                    if (last) {
                        size_t oi = (size_t)(gm + r) * T_LEN + t;
                        out_b[oi] = (_Float16)((float)out_b[oi] + v);
                    } else {
                        size_t ai = (size_t)(gm + r) * TP + GUARD + t;
                        aud_wr[ai] = (_Float16)((float)aud_rd[ai] + v);
                    }
                } else if (!last) {              // skip channels
                    size_t oi = (size_t)(gm + r - 256) * T_LEN + t;
                    out_b[oi] = (_Float16)((float)out_b[oi] + v);
                }
            }
        }
    }
}

// ------------------------------------------------------------- pack weights
__global__ __launch_bounds__(256) void pack_kernel(
    const float* __restrict__ cond_w, const float* __restrict__ in_w,
    const float* __restrict__ rs_w, const float* __restrict__ in_b,
    const float* __restrict__ cond_b,
    _Float16* __restrict__ W1h, _Float16* __restrict__ RSh,
    float* __restrict__ bias1)
{
    constexpr int SZ_W1 = NL * 512 * KTOT;       // 5,767,168
    constexpr int SZ_RS = NL * 512 * NC;         // 1,048,576
    int idx = blockIdx.x * 256 + threadIdx.x;
    if (idx < SZ_W1) {
        int lyr = idx / (512 * KTOT);
        int r1 = idx - lyr * (512 * KTOT);
        int m = r1 / KTOT;
        int k = r1 - m * KTOT;
        float v;
        if (k < NMEL) {
            v = cond_w[(size_t)(lyr * 512 + m) * NMEL + k];
        } else {
            int kin = k - NMEL;
            int kk = kin >> 8, cc = kin & 255;   // tap-major
            v = in_w[((size_t)(lyr * 512 + m) * NC + cc) * 3 + kk];
        }
        W1h[idx] = (_Float16)v;
    } else if (idx < SZ_W1 + SZ_RS) {
        int i2 = idx - SZ_W1;
        RSh[i2] = (_Float16)rs_w[i2];
    } else if (idx < SZ_W1 + SZ_RS + NL * 512) {
        int i3 = idx - SZ_W1 - SZ_RS;
        bias1[i3] = in_b[i3] + cond_b[i3];
    }
}

// ------------------------------------------------------------- spect -> fp16
__global__ __launch_bounds__(256) void spect_cvt_kernel(
    const float* __restrict__ spect, _Float16* __restrict__ spect_h)
{
    int i4 = blockIdx.x * 256 + threadIdx.x;     // NB*NMEL*T/4 threads
    float4 v = ((const float4*)spect)[i4];
    ushort4 o;
    o.x = __builtin_bit_cast(unsigned short, (_Float16)v.x);
    o.y = __builtin_bit_cast(unsigned short, (_Float16)v.y);
    o.z = __builtin_bit_cast(unsigned short, (_Float16)v.z);
    o.w = __builtin_bit_cast(unsigned short, (_Float16)v.w);
    ((ushort4*)spect_h)[i4] = o;
}

// ------------------------------------------------------------- guard zero
__global__ __launch_bounds__(256) void guard_zero_kernel(
    _Float16* __restrict__ audio0, _Float16* __restrict__ audio1)
{
    int idx = blockIdx.x * 256 + threadIdx.x;    // 262144 dwords
    int row = idx >> 7;
    int off = idx & 127;
    int dw  = (off < 64) ? off : (off + 4096);   // [0,64) U [4160,4224)
    unsigned* base = (unsigned*)((row >> 10) ? audio1 : audio0);
    base[(size_t)(row & 1023) * (TP / 2) + dw] = 0u;
}

// ------------------------------------------------------------- start conv
__global__ __launch_bounds__(256) void start_kernel(
    const float* __restrict__ audio_in,  // (B,4,T)
    const float* __restrict__ start_w,   // (256,4)
    const float* __restrict__ start_b,   // (256)
    _Float16* __restrict__ audio0,       // (B,256,TP) fp16 padded
    _Float16* __restrict__ outbuf)       // (B,256,T) fp16 -> zero
{
    int idx = blockIdx.x * 256 + threadIdx.x;
    int t = idx & (T_LEN - 1);
    int c = (idx >> 13) & (NC - 1);
    int b = idx >> 21;
    float acc = start_b[c];
    #pragma unroll
    for (int a = 0; a < 4; ++a)
        acc += start_w[c * 4 + a] * audio_in[((size_t)b * 4 + a) * T_LEN + t];
    audio0[(size_t)(b * NC + c) * TP + GUARD + t] = (_Float16)acc;
    outbuf[idx] = (_Float16)0.f;
}

// ------------------------------------------------------------- end conv
__global__ __launch_bounds__(256) void end_kernel(
    const _Float16* __restrict__ outbuf,
    const float* __restrict__ end_w,     // (8,256)
    const float* __restrict__ end_b,     // (8)
    float* __restrict__ out)             // (B,8,T)
{
    int idx = blockIdx.x * 256 + threadIdx.x;    // B*T threads
    int t = idx & (T_LEN - 1);
    int b = idx >> 13;
    const _Float16* ob = outbuf + (size_t)b * NC * T_LEN;
    float acc[8];
    #pragma unroll
    for (int o = 0; o < 8; ++o) acc[o] = end_b[o];
    for (int c = 0; c < NC; ++c) {
        float x = (float)ob[(size_t)c * T_LEN + t];
        #pragma unroll
        for (int o = 0; o < 8; ++o) acc[o] += end_w[o * NC + c] * x;
    }
    #pragma unroll
    for (int o = 0; o < 8; ++o)
        out[((size_t)b * 8 + o) * T_LEN + t] = acc[o];
}

// ------------------------------------------------------------- launcher
extern "C" void kernel_launch(void* const* d_in, const int* in_sizes, int n_in,
                              void* d_out, int out_size, void* d_ws, size_t ws_size,
                              hipStream_t stream)
{
    const float* spect    = (const float*)d_in[0];
    const float* audio_in = (const float*)d_in[1];
    const float* start_w  = (const float*)d_in[2];
    const float* start_b  = (const float*)d_in[3];
    const float* cond_w   = (const float*)d_in[4];
    const float* cond_b   = (const float*)d_in[5];
    const float* in_w     = (const float*)d_in[6];
    const float* in_b     = (const float*)d_in[7];
    const float* rs_w     = (const float*)d_in[8];
    const float* rs_b     = (const float*)d_in[9];
    const float* end_w    = (const float*)d_in[10];
    const float* end_b    = (const float*)d_in[11];
    float* out = (float*)d_out;

    // ws layout (bytes):
    //   W1h 11,534,336 | RSh 2,097,152 | bias1 16,384 | outbuf(f16) 16,777,216
    //   audio0 17,301,504 | audio1 17,301,504 | [spect_h 41,943,040]
    char* base = (char*)d_ws;
    _Float16* W1h    = (_Float16*)base;
    _Float16* RSh    = (_Float16*)(base + 11534336);
    float*    bias1  = (float*)(base + 13631488);
    _Float16* outbuf = (_Float16*)(base + 13647872);
    _Float16* audio0 = (_Float16*)(base + 30425088);
    _Float16* audio1 = (_Float16*)(base + 47726592);
    _Float16* spect_h = (_Float16*)(base + 65028096);
    const bool use_sh = (ws_size >= 106971136u);

    pack_kernel<<<26640, 256, 0, stream>>>(cond_w, in_w, rs_w, in_b, cond_b,
                                           W1h, RSh, bias1);
    if (use_sh)
        spect_cvt_kernel<<<(NB * NMEL * T_LEN) / 4 / 256, 256, 0, stream>>>(
            spect, spect_h);
    guard_zero_kernel<<<1024, 256, 0, stream>>>(audio0, audio1);
    start_kernel<<<(NB * NC * T_LEN) / 256, 256, 0, stream>>>(
        audio_in, start_w, start_b, audio0, outbuf);

    dim3 grid(T_LEN / NCOL, 1, NB);
    for (int i = 0; i < NL; ++i) {
        const _Float16* ard = (i & 1) ? audio1 : audio0;
        _Float16*       awr = (i & 1) ? audio0 : audio1;
        const _Float16* W1l = W1h + (size_t)i * 512 * KTOT;
        const _Float16* RSl = RSh + (size_t)i * 512 * NC;
        const float* b1l = bias1 + i * 512;
        const float* rbl = rs_b + i * 512;
        int dil = 1 << i;
        int last = (i == NL - 1) ? 1 : 0;
        if (use_sh)
            wavenet_layer<true><<<grid, 512, 0, stream>>>(
                ard, awr, spect, spect_h, W1l, b1l, RSl, rbl, outbuf, dil, last);
        else
            wavenet_layer<false><<<grid, 512, 0, stream>>>(
                ard, awr, spect, spect_h, W1l, b1l, RSl, rbl, outbuf, dil, last);
    }

    end_kernel<<<(NB * T_LEN) / 256, 256, 0, stream>>>(outbuf, end_w, end_b, out);
}